// Round 2
// baseline (5327.003 us; speedup 1.0000x reference)
//
#include <hip/hip_runtime.h>

// ---------------------------------------------------------------------------
// 2-layer tanh SimpleRNN, BATCH=256, SEQ=80, UNITS=2048 (fp32 in/out).
// Round 2: 256 WGs x 512 thr (8 waves). WG = one 64x64 output tile of one
// layer; K split 8-ways across waves; A/B fragments loaded global->reg with
// 2-deep pipeline (no LDS, no barriers in K-loop); LDS 2-pass reduction of
// the 8 K-partials; device-wide flag barrier per phase.
// ---------------------------------------------------------------------------

typedef _Float16 f16;
typedef _Float16 f16x2 __attribute__((ext_vector_type(2)));
typedef _Float16 f16x8 __attribute__((ext_vector_type(8)));
typedef float    f32x4 __attribute__((ext_vector_type(4)));

#define NWG    256
#define SEQ    80
#define EPAD   128
#define NKC0   68          // layer0 K = 2048 (U0) + 128 (x-pad) = 2176 = 68*32
#define NKC1   128         // layer1 K = 4096 ([W1;U1])

// ---- workspace layout (bytes) ----
#define FLAGS_OFF  0
#define HBUF_OFF   1024
#define HBUF_ONE   (256 * 4096 * 2)          // [256][4096] f16 (h0 | h1)
#define B0S_OFF    (HBUF_OFF + 2 * HBUF_ONE)
#define B0S_SIZE   (2048 * NKC0 * 32 * 2)    // 8.9 MB
#define B1S_OFF    (B0S_OFF + B0S_SIZE)
#define B1S_SIZE   (2048 * NKC1 * 32 * 2)    // 16.8 MB
#define XP_OFF     (B1S_OFF + B1S_SIZE)
#define XP_SIZE    (SEQ * 256 * EPAD * 2)    // 5.2 MB
#define WS_NEED    ((size_t)XP_OFF + XP_SIZE)

__device__ __forceinline__ float tanh_fast(float x) {
  x = fminf(15.f, fmaxf(-15.f, x));
  float e = __expf(2.f * x);
  return (e - 1.f) * __builtin_amdgcn_rcpf(e + 1.f);
}

// device-wide barrier: per-WG monotone flags, agent fences (round-1 proven)
__device__ __forceinline__ void gbar(int* flags, int target) {
  __syncthreads();                       // all waves' stores issued + drained
  if (threadIdx.x == 0) {
    __threadfence();                     // agent release (wbl2)
    __hip_atomic_store(&flags[blockIdx.x], target, __ATOMIC_RELAXED,
                       __HIP_MEMORY_SCOPE_AGENT);
  }
  if (threadIdx.x < NWG) {
    while (__hip_atomic_load(&flags[threadIdx.x], __ATOMIC_RELAXED,
                             __HIP_MEMORY_SCOPE_AGENT) < target)
      __builtin_amdgcn_s_sleep(2);
  }
  __syncthreads();
  __threadfence();                       // agent acquire (inv)
}

// ---------------------------------------------------------------------------
// prologue 1: weights -> fp16 MFMA B-fragment streams.
// frag (slice, kcg, n16) at B + frag*512 halfs, frag = (slice*NKC + kcg)*4 + n16
// lane l holds elems (k = kcg*32 + (l>>4)*8 + j, col = slice*64 + n16*16 + (l&15))
// ---------------------------------------------------------------------------
__global__ __launch_bounds__(256) void fmt_weights(
    const float* __restrict__ W0, const float* __restrict__ U0,
    const float* __restrict__ W1, const float* __restrict__ U1,
    char* __restrict__ ws)
{
  int frag = blockIdx.x * 4 + (threadIdx.x >> 6);
  int lane = threadIdx.x & 63, lr = lane & 15, lk = (lane >> 4) * 8;
  f16x8 h;
  f16* dst;
  if (frag < 32 * NKC0 * 4) {
    int slice = frag / (NKC0 * 4), rem = frag % (NKC0 * 4);
    int kcg = rem >> 2, n16 = rem & 3;
    int col = slice * 64 + n16 * 16 + lr;
#pragma unroll
    for (int j = 0; j < 8; ++j) {
      int k = kcg * 32 + lk + j;
      float v;
      if (k < 2048) v = U0[(size_t)k * 2048 + col];
      else { int e = k - 2048; v = (e < 100) ? W0[(size_t)e * 2048 + col] : 0.f; }
      h[j] = (f16)v;
    }
    dst = (f16*)(ws + B0S_OFF) + (size_t)frag * 512;
  } else {
    int fr = frag - 32 * NKC0 * 4;
    int slice = fr / (NKC1 * 4), rem = fr % (NKC1 * 4);
    int kcg = rem >> 2, n16 = rem & 3;
    int col = slice * 64 + n16 * 16 + lr;
#pragma unroll
    for (int j = 0; j < 8; ++j) {
      int k = kcg * 32 + lk + j;
      float v = (k < 2048) ? W1[(size_t)k * 2048 + col]
                           : U1[(size_t)(k - 2048) * 2048 + col];
      h[j] = (f16)v;
    }
    dst = (f16*)(ws + B1S_OFF) + (size_t)fr * 512;
  }
  *(f16x8*)(dst + lane * 8) = h;
}

// ---------------------------------------------------------------------------
// prologue 2: embedding lookup -> Xp[t][b][0..127] fp16 (cols >=100 zero)
// ---------------------------------------------------------------------------
__global__ __launch_bounds__(256) void embed_k(
    const int* __restrict__ inputs, const float* __restrict__ emb,
    char* __restrict__ ws)
{
  int r = blockIdx.x * 4 + (threadIdx.x >> 6);   // r = t*256 + b
  int lane = threadIdx.x & 63;
  int t = r >> 8, b = r & 255;
  int idx = inputs[b * SEQ + t];
  int e = lane * 2;
  f16x2 h;
  if (e < 100) {
    const float* src = emb + (size_t)idx * 100 + e;
    h[0] = (f16)src[0]; h[1] = (f16)src[1];
  } else { h[0] = (f16)0.f; h[1] = (f16)0.f; }
  *(f16x2*)(ws + XP_OFF + ((size_t)r * EPAD + e) * 2) = h;
}

// ---------------------------------------------------------------------------
// persistent RNN kernel.
// bid<128: layer0 tile; bid>=128: layer1. u = a*32 + b*8 + xcd ->
// cslice = xcd*4 + b (keeps the 4 row-WGs of a column slice on ONE XCD so the
// B slice stays L2-resident), m0 = a*64.
// phase p: layer0 computes h0[p] (p<80); layer1 computes h1[p-1] (zero @ p=0).
// ---------------------------------------------------------------------------
__global__ __launch_bounds__(512, 2) void rnn_persist(
    const float* __restrict__ b0v, const float* __restrict__ b1v,
    char* __restrict__ ws)
{
  __shared__ f32x4 red[8][8][64];                // 64 KiB reduction scratch

  const int bid = blockIdx.x;
  const int tid = threadIdx.x;
  const int wv = tid >> 6, lane = tid & 63;
  const int lr = lane & 15, lk = (lane >> 4) * 8;

  int* flags = (int*)(ws + FLAGS_OFF);
  f16* HbA = (f16*)(ws + HBUF_OFF);
  f16* HbB = (f16*)(ws + HBUF_OFF + HBUF_ONE);
  const f16* Xp = (const f16*)(ws + XP_OFF);

  const bool isL0 = bid < 128;
  const int u = isL0 ? bid : bid - 128;
  const int cslice = (u & 7) * 4 + ((u >> 3) & 3);   // 0..31
  const int m0 = (u >> 5) * 64;                      // 0,64,128,192
  const int n0 = cslice * 64;
  const f16* Bst = (const f16*)(ws + (isL0 ? B0S_OFF : B1S_OFF));
  const int NKCg = isL0 ? NKC0 : NKC1;
  const int kcgb = isL0 ? wv * 9 : wv * 16;          // wave's global kc base
  const int nkc  = isL0 ? (wv < 7 ? 9 : 5) : 16;     // kc chunks this wave
  const int kb   = kcgb * 32;
  const float* bias = isL0 ? b0v : b1v;
  const int outh = isL0 ? 0 : 2048;

  const f16* bp = Bst + ((size_t)cslice * NKCg + kcgb) * 2048 + lane * 8;

  size_t aoff[4];                                     // h-row offsets (halfs)
#pragma unroll
  for (int rf = 0; rf < 4; ++rf)
    aoff[rf] = (size_t)(m0 + rf * 16 + lr) * 4096 + lk;

  for (int p = 0; p <= 80; ++p) {
    const f16* Hr = ((p + 1) & 1) ? HbB : HbA;
    f16*       Hw = (p & 1) ? HbB : HbA;
    const bool active = isL0 ? (p < 80) : true;
    const bool fzero  = (!isL0) && (p == 0);

    f32x4 acc[4][4];
#pragma unroll
    for (int a = 0; a < 4; ++a)
#pragma unroll
      for (int b = 0; b < 4; ++b) acc[a][b] = {0.f, 0.f, 0.f, 0.f};

    if (active && !fzero) {
      size_t xoff[4];
      if (isL0) {
#pragma unroll
        for (int rf = 0; rf < 4; ++rf)
          xoff[rf] = ((size_t)p * 256 + m0 + rf * 16 + lr) * EPAD + lk;
      }
      f16x8 aA[4], bA[4], aB[4], bB[4];

      auto LD = [&](int kc, f16x8 (&a)[4], f16x8 (&b)[4]) {
        const int kk = kb + kc * 32;
#pragma unroll
        for (int cf = 0; cf < 4; ++cf)
          b[cf] = *(const f16x8*)(bp + (size_t)kc * 2048 + cf * 512);
        if (isL0 && kk >= 2048) {
#pragma unroll
          for (int rf = 0; rf < 4; ++rf)
            a[rf] = *(const f16x8*)(Xp + xoff[rf] + (kk - 2048));
        } else {
#pragma unroll
          for (int rf = 0; rf < 4; ++rf)
            a[rf] = *(const f16x8*)(Hr + aoff[rf] + kk);
        }
      };
      auto ST = [&](f16x8 (&a)[4], f16x8 (&b)[4]) {
#pragma unroll
        for (int cf = 0; cf < 4; ++cf)
#pragma unroll
          for (int rf = 0; rf < 4; ++rf)
            acc[rf][cf] = __builtin_amdgcn_mfma_f32_16x16x32_f16(
                a[rf], b[cf], acc[rf][cf], 0, 0, 0);
      };

      LD(0, aA, bA);                       // 2-deep pipeline, no syncs
      int kc = 0;
      while (true) {
        if (kc + 1 < nkc) LD(kc + 1, aB, bB);
        ST(aA, bA);
        if (++kc >= nkc) break;
        if (kc + 1 < nkc) LD(kc + 1, aA, bA);
        ST(aB, bB);
        if (++kc >= nkc) break;
      }
    }

    if (active) {
      // 2-pass 8-way reduction: pass t covers rf in {2t, 2t+1} (8 frags).
#pragma unroll
      for (int t = 0; t < 2; ++t) {
        if (t) __syncthreads();            // pass-0 readers done before rewrite
#pragma unroll
        for (int rr = 0; rr < 2; ++rr)
#pragma unroll
          for (int cf = 0; cf < 4; ++cf)
            red[wv][rr * 4 + cf][lane] = acc[2 * t + rr][cf];
        __syncthreads();
        {
          const int rf = 2 * t + (wv >> 2), cf = wv & 3;  // frag idx = wv
          f32x4 s = red[0][wv][lane];
#pragma unroll
          for (int ow = 1; ow < 8; ++ow) s += red[ow][wv][lane];
          const int gcol = n0 + cf * 16 + lr;
          const float bv = bias[gcol];
#pragma unroll
          for (int r = 0; r < 4; ++r) {
            const int gr = m0 + rf * 16 + (lane >> 4) * 4 + r;
            const float v = fzero ? 0.f : tanh_fast(s[r] + bv);
            Hw[(size_t)gr * 4096 + outh + gcol] = (f16)v;
          }
        }
      }
    }
    if (p < 80) gbar(flags, p + 1);
  }
}

// ---------------------------------------------------------------------------
// epilogue: logits = sigmoid(h1[79] @ Wo + bo) -> 256 fp32
// ---------------------------------------------------------------------------
__global__ __launch_bounds__(256) void logits_k(
    const char* __restrict__ ws, const float* __restrict__ Wo,
    const float* __restrict__ bo, float* __restrict__ out)
{
  int row = blockIdx.x * 4 + (threadIdx.x >> 6);
  int lane = threadIdx.x & 63;
  const f16* h1 = (const f16*)(ws + HBUF_OFF) + (size_t)row * 4096 + 2048;
  float s = 0.f;
#pragma unroll
  for (int it = 0; it < 4; ++it) {
    int k = it * 512 + lane * 8;
    f16x8 hv = *(const f16x8*)(h1 + k);
    const float4* wp = (const float4*)(Wo + k);
    float4 w0 = wp[0], w1 = wp[1];
    s += (float)hv[0] * w0.x + (float)hv[1] * w0.y + (float)hv[2] * w0.z + (float)hv[3] * w0.w;
    s += (float)hv[4] * w1.x + (float)hv[5] * w1.y + (float)hv[6] * w1.z + (float)hv[7] * w1.w;
  }
#pragma unroll
  for (int off = 32; off > 0; off >>= 1) s += __shfl_down(s, off);
  if (lane == 0) out[row] = 1.f / (1.f + __expf(-(s + bo[0])));
}

// ---------------------------------------------------------------------------
extern "C" void kernel_launch(void* const* d_in, const int* in_sizes, int n_in,
                              void* d_out, int out_size, void* d_ws, size_t ws_size,
                              hipStream_t stream)
{
  (void)in_sizes; (void)n_in; (void)out_size;
  const int*   inputs = (const int*)d_in[0];
  const float* emb    = (const float*)d_in[1];
  const float* W0     = (const float*)d_in[2];
  const float* U0     = (const float*)d_in[3];
  const float* b0     = (const float*)d_in[4];
  const float* W1     = (const float*)d_in[5];
  const float* U1     = (const float*)d_in[6];
  const float* b1     = (const float*)d_in[7];
  const float* Wo     = (const float*)d_in[8];
  const float* bo     = (const float*)d_in[9];
  char* ws = (char*)d_ws;
  if (ws_size < WS_NEED) return;   // visible validation failure if too small

  // zero barrier flags + both h buffers (h0_init = h1_init = 0)
  hipMemsetAsync(ws, 0, HBUF_OFF + 2 * HBUF_ONE, stream);
  fmt_weights<<<6272, 256, 0, stream>>>(W0, U0, W1, U1, ws);
  embed_k<<<5120, 256, 0, stream>>>(inputs, emb, ws);
  rnn_persist<<<NWG, 512, 0, stream>>>(b0, b1, ws);
  logits_k<<<64, 256, 0, stream>>>(ws, Wo, bo, (float*)d_out);
}

// Round 3
// 3215.812 us; speedup vs baseline: 1.6565x; 1.6565x over previous
//
#include <hip/hip_runtime.h>

// ---------------------------------------------------------------------------
// 2-layer tanh SimpleRNN, BATCH=256, SEQ=80, UNITS=2048 (fp32 in/out).
// Round 3: same 256-WG / 512-thr / K-split-across-waves structure as round 2,
// but NO cache-invalidating fences. h-buffers use per-instruction coherence
// (sc0 sc1 loads/stores, inline asm); weights/Xp stay L2-cached across all
// phases. K-loop = all-asm loads + counted vmcnt (3-deep pipeline).
// ---------------------------------------------------------------------------

typedef _Float16 f16;
typedef _Float16 f16x2 __attribute__((ext_vector_type(2)));
typedef _Float16 f16x8 __attribute__((ext_vector_type(8)));
typedef float    f32x4 __attribute__((ext_vector_type(4)));

#define NWG    256
#define SEQ    80
#define EPAD   128
#define NKC0   68          // layer0 K = 2048 (U0) + 128 (x-pad) = 2176 = 68*32
#define NKC1   128         // layer1 K = 4096 ([W1;U1])

// ---- workspace layout (bytes) ----
#define FLAGS_OFF  0
#define HBUF_OFF   1024
#define HBUF_ONE   (256 * 4096 * 2)          // [256][4096] f16 (h0 | h1)
#define B0S_OFF    (HBUF_OFF + 2 * HBUF_ONE)
#define B0S_SIZE   (2048 * NKC0 * 32 * 2)    // 8.9 MB
#define B1S_OFF    (B0S_OFF + B0S_SIZE)
#define B1S_SIZE   (2048 * NKC1 * 32 * 2)    // 16.8 MB
#define XP_OFF     (B1S_OFF + B1S_SIZE)
#define XP_SIZE    (SEQ * 256 * EPAD * 2)    // 5.2 MB
#define WS_NEED    ((size_t)XP_OFF + XP_SIZE)

__device__ __forceinline__ float tanh_fast(float x) {
  x = fminf(15.f, fmaxf(-15.f, x));
  float e = __expf(2.f * x);
  return (e - 1.f) * __builtin_amdgcn_rcpf(e + 1.f);
}

// --- inline-asm memory ops (all K-loop loads are asm => exact vmcnt count) ---
__device__ __forceinline__ f16x8 ldg16_coh(const f16* p) {   // bypass L1/L2
  f16x8 r;
  asm volatile("global_load_dwordx4 %0, %1, off sc0 sc1" : "=v"(r) : "v"(p));
  return r;
}
__device__ __forceinline__ f16x8 ldg16(const f16* p) {       // normal cached
  f16x8 r;
  asm volatile("global_load_dwordx4 %0, %1, off" : "=v"(r) : "v"(p));
  return r;
}
__device__ __forceinline__ void stg16_coh(f16* p, f16x8 v) { // write-through
  asm volatile("global_store_dwordx4 %0, %1, off sc0 sc1" :: "v"(p), "v"(v) : "memory");
}
// counted waits; tie the consumed registers so MFMAs can't hoist above
#define VWAIT(name, n)                                                        \
__device__ __forceinline__ void name(f16x8 (&a)[4], f16x8 (&b)[4]) {          \
  asm volatile("s_waitcnt vmcnt(" #n ")"                                      \
    : "+v"(a[0]), "+v"(a[1]), "+v"(a[2]), "+v"(a[3]),                         \
      "+v"(b[0]), "+v"(b[1]), "+v"(b[2]), "+v"(b[3]) :: "memory");            \
}
VWAIT(vwait16, 16)
VWAIT(vwait8, 8)
VWAIT(vwait0, 0)

// device-wide barrier: drain + relaxed agent flag; NO cache fences.
__device__ __forceinline__ void gbar(int* flags, int target) {
  asm volatile("s_waitcnt vmcnt(0)" ::: "memory");   // coherent stores visible
  __syncthreads();
  if (threadIdx.x == 0)
    __hip_atomic_store(&flags[blockIdx.x], target, __ATOMIC_RELAXED,
                       __HIP_MEMORY_SCOPE_AGENT);
  if (threadIdx.x < NWG) {
    while (__hip_atomic_load(&flags[threadIdx.x], __ATOMIC_RELAXED,
                             __HIP_MEMORY_SCOPE_AGENT) < target)
      __builtin_amdgcn_s_sleep(2);
  }
  __syncthreads();
}

// ---------------------------------------------------------------------------
// prologue 1: weights -> fp16 MFMA B-fragment streams (unchanged from r2)
// ---------------------------------------------------------------------------
__global__ __launch_bounds__(256) void fmt_weights(
    const float* __restrict__ W0, const float* __restrict__ U0,
    const float* __restrict__ W1, const float* __restrict__ U1,
    char* __restrict__ ws)
{
  int frag = blockIdx.x * 4 + (threadIdx.x >> 6);
  int lane = threadIdx.x & 63, lr = lane & 15, lk = (lane >> 4) * 8;
  f16x8 h;
  f16* dst;
  if (frag < 32 * NKC0 * 4) {
    int slice = frag / (NKC0 * 4), rem = frag % (NKC0 * 4);
    int kcg = rem >> 2, n16 = rem & 3;
    int col = slice * 64 + n16 * 16 + lr;
#pragma unroll
    for (int j = 0; j < 8; ++j) {
      int k = kcg * 32 + lk + j;
      float v;
      if (k < 2048) v = U0[(size_t)k * 2048 + col];
      else { int e = k - 2048; v = (e < 100) ? W0[(size_t)e * 2048 + col] : 0.f; }
      h[j] = (f16)v;
    }
    dst = (f16*)(ws + B0S_OFF) + (size_t)frag * 512;
  } else {
    int fr = frag - 32 * NKC0 * 4;
    int slice = fr / (NKC1 * 4), rem = fr % (NKC1 * 4);
    int kcg = rem >> 2, n16 = rem & 3;
    int col = slice * 64 + n16 * 16 + lr;
#pragma unroll
    for (int j = 0; j < 8; ++j) {
      int k = kcg * 32 + lk + j;
      float v = (k < 2048) ? W1[(size_t)k * 2048 + col]
                           : U1[(size_t)(k - 2048) * 2048 + col];
      h[j] = (f16)v;
    }
    dst = (f16*)(ws + B1S_OFF) + (size_t)fr * 512;
  }
  *(f16x8*)(dst + lane * 8) = h;
}

// ---------------------------------------------------------------------------
// prologue 2: embedding lookup -> Xp[t][b][0..127] fp16 (cols >=100 zero)
// ---------------------------------------------------------------------------
__global__ __launch_bounds__(256) void embed_k(
    const int* __restrict__ inputs, const float* __restrict__ emb,
    char* __restrict__ ws)
{
  int r = blockIdx.x * 4 + (threadIdx.x >> 6);   // r = t*256 + b
  int lane = threadIdx.x & 63;
  int t = r >> 8, b = r & 255;
  int idx = inputs[b * SEQ + t];
  int e = lane * 2;
  f16x2 h;
  if (e < 100) {
    const float* src = emb + (size_t)idx * 100 + e;
    h[0] = (f16)src[0]; h[1] = (f16)src[1];
  } else { h[0] = (f16)0.f; h[1] = (f16)0.f; }
  *(f16x2*)(ws + XP_OFF + ((size_t)r * EPAD + e) * 2) = h;
}

// ---------------------------------------------------------------------------
// K-tile loop: 3-deep all-asm pipeline with counted vmcnt.
// Each LD issues exactly 8 dwordx4 (4 B normal + 4 A coherent).
// ---------------------------------------------------------------------------
template <int NKC, bool L0T>
__device__ __forceinline__ void ktile(
    const f16* __restrict__ Hr, const f16* __restrict__ Xp,
    const f16* __restrict__ bp, const size_t* aoff, const size_t* xoff,
    int kb, f32x4 (&acc)[4][4])
{
  f16x8 A[3][4], B[3][4];
  auto LD = [&](int kc, f16x8 (&a)[4], f16x8 (&b)[4]) {
#pragma unroll
    for (int cf = 0; cf < 4; ++cf)
      b[cf] = ldg16(bp + (size_t)kc * 2048 + cf * 512);
    int kk = kb + kc * 32;
    if (L0T && kk >= 2048) {
#pragma unroll
      for (int rf = 0; rf < 4; ++rf)
        a[rf] = ldg16_coh(Xp + xoff[rf] + (kk - 2048));
    } else {
#pragma unroll
      for (int rf = 0; rf < 4; ++rf)
        a[rf] = ldg16_coh(Hr + aoff[rf] + kk);
    }
  };
  auto ST = [&](f16x8 (&a)[4], f16x8 (&b)[4]) {
#pragma unroll
    for (int cf = 0; cf < 4; ++cf)
#pragma unroll
      for (int rf = 0; rf < 4; ++rf)
        acc[rf][cf] = __builtin_amdgcn_mfma_f32_16x16x32_f16(
            a[rf], b[cf], acc[rf][cf], 0, 0, 0);
  };

  LD(0, A[0], B[0]);
  if (NKC > 1) LD(1, A[1], B[1]);
#pragma unroll
  for (int kc = 0; kc < NKC; ++kc) {
    f16x8 (&a)[4] = A[kc % 3];
    f16x8 (&b)[4] = B[kc % 3];
    if (kc + 2 < NKC) { LD(kc + 2, A[(kc + 2) % 3], B[(kc + 2) % 3]); vwait16(a, b); }
    else if (kc + 1 < NKC) vwait8(a, b);
    else vwait0(a, b);
    ST(a, b);
  }
}

// ---------------------------------------------------------------------------
// persistent RNN kernel (structure as round 2; coherent h path, fence-free bar)
// ---------------------------------------------------------------------------
__global__ __launch_bounds__(512, 2) void rnn_persist(
    const float* __restrict__ b0v, const float* __restrict__ b1v,
    char* __restrict__ ws)
{
  __shared__ f32x4 red[8][8][64];                // 64 KiB reduction scratch
  __shared__ f16 T[64 * 64];                     // 8 KiB output-tile transpose

  const int bid = blockIdx.x;
  const int tid = threadIdx.x;
  const int wv = tid >> 6, lane = tid & 63;
  const int lr = lane & 15, lk = (lane >> 4) * 8;

  int* flags = (int*)(ws + FLAGS_OFF);
  f16* HbA = (f16*)(ws + HBUF_OFF);
  f16* HbB = (f16*)(ws + HBUF_OFF + HBUF_ONE);
  const f16* Xp = (const f16*)(ws + XP_OFF);

  const bool isL0 = bid < 128;
  const int u = isL0 ? bid : bid - 128;
  const int cslice = (u & 7) * 4 + ((u >> 3) & 3);   // spread col-slices; B/XCD ~3.2MB
  const int m0 = (u >> 5) * 64;
  const int n0 = cslice * 64;
  const f16* Bst = (const f16*)(ws + (isL0 ? B0S_OFF : B1S_OFF));
  const int NKCg = isL0 ? NKC0 : NKC1;
  const int kcgb = isL0 ? wv * 9 : wv * 16;          // wave's first K32 chunk
  const int kb   = kcgb * 32;
  const float* bias = isL0 ? b0v : b1v;
  const int outh = isL0 ? 0 : 2048;

  const f16* bp = Bst + ((size_t)cslice * NKCg + kcgb) * 2048 + lane * 8;

  size_t aoff[4], xoff[4];
#pragma unroll
  for (int rf = 0; rf < 4; ++rf)
    aoff[rf] = (size_t)(m0 + rf * 16 + lr) * 4096 + lk;

  for (int p = 0; p <= 80; ++p) {
    const f16* Hr = ((p + 1) & 1) ? HbB : HbA;
    f16*       Hw = (p & 1) ? HbB : HbA;
    const bool active = isL0 ? (p < 80) : true;
    const bool fzero  = (!isL0) && (p == 0);

    f32x4 acc[4][4];
#pragma unroll
    for (int a = 0; a < 4; ++a)
#pragma unroll
      for (int b = 0; b < 4; ++b) acc[a][b] = {0.f, 0.f, 0.f, 0.f};

    if (active && !fzero) {
      if (isL0) {
#pragma unroll
        for (int rf = 0; rf < 4; ++rf)
          xoff[rf] = ((size_t)p * 256 + m0 + rf * 16 + lr) * EPAD + lk;
        if (wv < 7) ktile<9, true>(Hr, Xp, bp, aoff, xoff, kb, acc);
        else        ktile<5, true>(Hr, Xp, bp, aoff, xoff, kb, acc);
      } else {
        ktile<16, false>(Hr, Xp, bp, aoff, xoff, kb, acc);
      }
    }

    if (active) {
      // 2-pass 8-way K-reduction (as r2), then tanh -> swizzled f16 LDS tile
#pragma unroll
      for (int t = 0; t < 2; ++t) {
        if (t) __syncthreads();            // pass-0 readers done before rewrite
#pragma unroll
        for (int rr = 0; rr < 2; ++rr)
#pragma unroll
          for (int cf = 0; cf < 4; ++cf)
            red[wv][rr * 4 + cf][lane] = acc[2 * t + rr][cf];
        __syncthreads();
        {
          const int rf = 2 * t + (wv >> 2), cf = wv & 3;  // frag idx = wv
          f32x4 s = red[0][wv][lane];
#pragma unroll
          for (int ow = 1; ow < 8; ++ow) s += red[ow][wv][lane];
          const int tcol = cf * 16 + lr;
          const float bv = bias[n0 + tcol];
          const int trow = rf * 16 + (lane >> 4) * 4;
#pragma unroll
          for (int r = 0; r < 4; ++r) {
            const float v = fzero ? 0.f : tanh_fast(s[r] + bv);
            T[(trow + r) * 64 + (tcol ^ (((trow + r) & 3) << 4))] = (f16)v;
          }
        }
      }
      __syncthreads();
      // coalesced coherent store: one 16B sc0sc1 store per thread
      {
        const int row = tid >> 3, c8 = (tid & 7) * 8;
        f16x8 val = *(const f16x8*)(T + row * 64 + (c8 ^ ((row & 3) << 4)));
        stg16_coh(Hw + (size_t)(m0 + row) * 4096 + outh + n0 + c8, val);
      }
    }
    if (p < 80) gbar(flags, p + 1);
  }
}

// ---------------------------------------------------------------------------
// epilogue: logits = sigmoid(h1[79] @ Wo + bo) -> 256 fp32
// ---------------------------------------------------------------------------
__global__ __launch_bounds__(256) void logits_k(
    const char* __restrict__ ws, const float* __restrict__ Wo,
    const float* __restrict__ bo, float* __restrict__ out)
{
  int row = blockIdx.x * 4 + (threadIdx.x >> 6);
  int lane = threadIdx.x & 63;
  const f16* h1 = (const f16*)(ws + HBUF_OFF) + (size_t)row * 4096 + 2048;
  float s = 0.f;
#pragma unroll
  for (int it = 0; it < 4; ++it) {
    int k = it * 512 + lane * 8;
    f16x8 hv = *(const f16x8*)(h1 + k);
    const float4* wp = (const float4*)(Wo + k);
    float4 w0 = wp[0], w1 = wp[1];
    s += (float)hv[0] * w0.x + (float)hv[1] * w0.y + (float)hv[2] * w0.z + (float)hv[3] * w0.w;
    s += (float)hv[4] * w1.x + (float)hv[5] * w1.y + (float)hv[6] * w1.z + (float)hv[7] * w1.w;
  }
#pragma unroll
  for (int off = 32; off > 0; off >>= 1) s += __shfl_down(s, off);
  if (lane == 0) out[row] = 1.f / (1.f + __expf(-(s + bo[0])));
}

// ---------------------------------------------------------------------------
extern "C" void kernel_launch(void* const* d_in, const int* in_sizes, int n_in,
                              void* d_out, int out_size, void* d_ws, size_t ws_size,
                              hipStream_t stream)
{
  (void)in_sizes; (void)n_in; (void)out_size;
  const int*   inputs = (const int*)d_in[0];
  const float* emb    = (const float*)d_in[1];
  const float* W0     = (const float*)d_in[2];
  const float* U0     = (const float*)d_in[3];
  const float* b0     = (const float*)d_in[4];
  const float* W1     = (const float*)d_in[5];
  const float* U1     = (const float*)d_in[6];
  const float* b1     = (const float*)d_in[7];
  const float* Wo     = (const float*)d_in[8];
  const float* bo     = (const float*)d_in[9];
  char* ws = (char*)d_ws;
  if (ws_size < WS_NEED) return;   // visible validation failure if too small

  // zero barrier flags + both h buffers (h0_init = h1_init = 0)
  hipMemsetAsync(ws, 0, HBUF_OFF + 2 * HBUF_ONE, stream);
  fmt_weights<<<6272, 256, 0, stream>>>(W0, U0, W1, U1, ws);
  embed_k<<<5120, 256, 0, stream>>>(inputs, emb, ws);
  rnn_persist<<<NWG, 512, 0, stream>>>(b0, b1, ws);
  logits_k<<<64, 256, 0, stream>>>(ws, Wo, bo, (float*)d_out);
}

// Round 4
// 2874.985 us; speedup vs baseline: 1.8529x; 1.1185x over previous
//
#include <hip/hip_runtime.h>

// ---------------------------------------------------------------------------
// 2-layer tanh SimpleRNN, BATCH=256, SEQ=80, UNITS=2048 (fp32 in/out).
// Round 4: per-timestep h buffers (no address reuse) => A-reads are normal
// cached loads (L2-served, no staleness possible); h stores write-through
// (sc0 sc1) so they're L3-visible after the global barrier. Fallback to
// 3-slot rotation + sc1 loads if ws is too small for 162 slots.
// ---------------------------------------------------------------------------

typedef _Float16 f16;
typedef _Float16 f16x2 __attribute__((ext_vector_type(2)));
typedef _Float16 f16x8 __attribute__((ext_vector_type(8)));
typedef float    f32x4 __attribute__((ext_vector_type(4)));

#define NWG    256
#define SEQ    80
#define EPAD   128
#define NKC0   68          // layer0 K chunks: 2048 (U0) + 128 (x-pad) = 68*32
#define NKC1   128         // layer1 K chunks: 4096 ([W1;U1])

// ---- workspace layout (bytes) ----
#define FLAGS_OFF   0
#define B0S_OFF     1024
#define B0S_SIZE    (2176 * 2048 * 2)        //  8,912,896
#define B1S_OFF     (B0S_OFF + B0S_SIZE)
#define B1S_SIZE    (4096 * 2048 * 2)        // 16,777,216
#define XP_OFF      (B1S_OFF + B1S_SIZE)
#define XP_SIZE     (SEQ * 256 * EPAD * 2)   //  5,242,880
#define H0_OFF      (XP_OFF + XP_SIZE)       // 30,934,016
#define HSLOT       (256 * 2048 * 2)         //  1 MiB per h slot
#define HSLOT_H     (256 * 2048)             //  halfs per slot
#define WS_FULL     ((size_t)H0_OFF + (size_t)162 * HSLOT)  // ~192 MB
#define WS_MIN      ((size_t)H0_OFF + (size_t)6 * HSLOT)

__device__ __forceinline__ float tanh_fast(float x) {
  x = fminf(15.f, fmaxf(-15.f, x));
  float e = __expf(2.f * x);
  return (e - 1.f) * __builtin_amdgcn_rcpf(e + 1.f);
}

// --- inline-asm memory ops (K-loop loads all asm => exact vmcnt counting) ---
__device__ __forceinline__ f16x8 ldg16_coh(const f16* p) {   // bypass L1+L2
  f16x8 r;
  asm volatile("global_load_dwordx4 %0, %1, off sc0 sc1" : "=v"(r) : "v"(p));
  return r;
}
__device__ __forceinline__ f16x8 ldg16(const f16* p) {       // normal cached
  f16x8 r;
  asm volatile("global_load_dwordx4 %0, %1, off" : "=v"(r) : "v"(p));
  return r;
}
__device__ __forceinline__ void stg16_coh(f16* p, f16x8 v) { // write-through
  asm volatile("global_store_dwordx4 %0, %1, off sc0 sc1" :: "v"(p), "v"(v) : "memory");
}
// counted waits; tie consumed regs so MFMAs can't hoist above the wait
#define VWAIT(name, n)                                                        \
__device__ __forceinline__ void name(f16x8 (&a)[4], f16x8 (&b)[4]) {          \
  asm volatile("s_waitcnt vmcnt(" #n ")"                                      \
    : "+v"(a[0]), "+v"(a[1]), "+v"(a[2]), "+v"(a[3]),                         \
      "+v"(b[0]), "+v"(b[1]), "+v"(b[2]), "+v"(b[3]) :: "memory");            \
}
VWAIT(vwait16, 16)
VWAIT(vwait8, 8)
VWAIT(vwait0, 0)

// device-wide barrier: vmcnt drain + relaxed agent flags; NO cache fences.
__device__ __forceinline__ void gbar(int* flags, int target) {
  asm volatile("s_waitcnt vmcnt(0)" ::: "memory");   // sc1 stores at L3
  __syncthreads();
  if (threadIdx.x == 0)
    __hip_atomic_store(&flags[blockIdx.x], target, __ATOMIC_RELAXED,
                       __HIP_MEMORY_SCOPE_AGENT);
  if (threadIdx.x < NWG) {
    while (__hip_atomic_load(&flags[threadIdx.x], __ATOMIC_RELAXED,
                             __HIP_MEMORY_SCOPE_AGENT) < target)
      __builtin_amdgcn_s_sleep(2);
  }
  __syncthreads();
}

// ---------------------------------------------------------------------------
// prologue 1: weights -> fp16 MFMA B-fragment streams (as r2/r3)
// ---------------------------------------------------------------------------
__global__ __launch_bounds__(256) void fmt_weights(
    const float* __restrict__ W0, const float* __restrict__ U0,
    const float* __restrict__ W1, const float* __restrict__ U1,
    char* __restrict__ ws)
{
  int frag = blockIdx.x * 4 + (threadIdx.x >> 6);
  int lane = threadIdx.x & 63, lr = lane & 15, lk = (lane >> 4) * 8;
  f16x8 h;
  f16* dst;
  if (frag < 32 * NKC0 * 4) {
    int slice = frag / (NKC0 * 4), rem = frag % (NKC0 * 4);
    int kcg = rem >> 2, n16 = rem & 3;
    int col = slice * 64 + n16 * 16 + lr;
#pragma unroll
    for (int j = 0; j < 8; ++j) {
      int k = kcg * 32 + lk + j;
      float v;
      if (k < 2048) v = U0[(size_t)k * 2048 + col];
      else { int e = k - 2048; v = (e < 100) ? W0[(size_t)e * 2048 + col] : 0.f; }
      h[j] = (f16)v;
    }
    dst = (f16*)(ws + B0S_OFF) + (size_t)frag * 512;
  } else {
    int fr = frag - 32 * NKC0 * 4;
    int slice = fr / (NKC1 * 4), rem = fr % (NKC1 * 4);
    int kcg = rem >> 2, n16 = rem & 3;
    int col = slice * 64 + n16 * 16 + lr;
#pragma unroll
    for (int j = 0; j < 8; ++j) {
      int k = kcg * 32 + lk + j;
      float v = (k < 2048) ? W1[(size_t)k * 2048 + col]
                           : U1[(size_t)(k - 2048) * 2048 + col];
      h[j] = (f16)v;
    }
    dst = (f16*)(ws + B1S_OFF) + (size_t)fr * 512;
  }
  *(f16x8*)(dst + lane * 8) = h;
}

// ---------------------------------------------------------------------------
// prologue 2: embedding lookup -> Xp[t][b][0..127] fp16 (cols >=100 zero)
// ---------------------------------------------------------------------------
__global__ __launch_bounds__(256) void embed_k(
    const int* __restrict__ inputs, const float* __restrict__ emb,
    char* __restrict__ ws)
{
  int r = blockIdx.x * 4 + (threadIdx.x >> 6);   // r = t*256 + b
  int lane = threadIdx.x & 63;
  int t = r >> 8, b = r & 255;
  int idx = inputs[b * SEQ + t];
  int e = lane * 2;
  f16x2 h;
  if (e < 100) {
    const float* src = emb + (size_t)idx * 100 + e;
    h[0] = (f16)src[0]; h[1] = (f16)src[1];
  } else { h[0] = (f16)0.f; h[1] = (f16)0.f; }
  *(f16x2*)(ws + XP_OFF + ((size_t)r * EPAD + e) * 2) = h;
}

// ---------------------------------------------------------------------------
// K-tile loop: 3-deep all-asm pipeline with counted vmcnt.
// A base Ab (stride 2048); if L0T, kk>=2048 switches to Xp (stride EPAD).
// ---------------------------------------------------------------------------
template <int NKC, bool L0T, bool COH>
__device__ __forceinline__ void ktile(
    const f16* __restrict__ Ab, const f16* __restrict__ Xp,
    const f16* __restrict__ bp, const size_t* aoff, const size_t* xoff,
    int kb, f32x4 (&acc)[4][4])
{
  f16x8 A[3][4], B[3][4];
  auto LD = [&](int kc, f16x8 (&a)[4], f16x8 (&b)[4]) {
#pragma unroll
    for (int cf = 0; cf < 4; ++cf)
      b[cf] = ldg16(bp + (size_t)kc * 2048 + cf * 512);
    int kk = kb + kc * 32;
    if (L0T && kk >= 2048) {
#pragma unroll
      for (int rf = 0; rf < 4; ++rf)
        a[rf] = ldg16(Xp + xoff[rf] + (kk - 2048));   // Xp: read-only, cached
    } else {
#pragma unroll
      for (int rf = 0; rf < 4; ++rf) {
        const f16* p = Ab + aoff[rf] + kk;
        if (COH) a[rf] = ldg16_coh(p); else a[rf] = ldg16(p);
      }
    }
  };
  auto ST = [&](f16x8 (&a)[4], f16x8 (&b)[4]) {
#pragma unroll
    for (int cf = 0; cf < 4; ++cf)
#pragma unroll
      for (int rf = 0; rf < 4; ++rf)
        acc[rf][cf] = __builtin_amdgcn_mfma_f32_16x16x32_f16(
            a[rf], b[cf], acc[rf][cf], 0, 0, 0);
  };

  LD(0, A[0], B[0]);
  if (NKC > 1) LD(1, A[1], B[1]);
#pragma unroll
  for (int kc = 0; kc < NKC; ++kc) {
    f16x8 (&a)[4] = A[kc % 3];
    f16x8 (&b)[4] = B[kc % 3];
    if (kc + 2 < NKC) { LD(kc + 2, A[(kc + 2) % 3], B[(kc + 2) % 3]); vwait16(a, b); }
    else if (kc + 1 < NKC) vwait8(a, b);
    else vwait0(a, b);
    ST(a, b);
  }
}

// ---------------------------------------------------------------------------
// persistent RNN kernel. 128 WGs layer0 + 128 WGs layer1, 64x64 tiles,
// K split across the 8 waves, LDS reduction, per-timestep h slots.
//   H0 slot idx for h0[t] = (t+1) % NBUF ; H1 slot idx for h1[t] = (t+1) % NBUF
// phase p: layer0 computes h0[p] (reads H0[p-1], Xp[p]); layer1 computes
// h1[p-1] (reads H0[p-1], H1[p-2]; zero at p=0).
// ---------------------------------------------------------------------------
template <int NBUF, bool COH>
__global__ __launch_bounds__(512, 2) void rnn_persist(
    const float* __restrict__ b0v, const float* __restrict__ b1v,
    char* __restrict__ ws)
{
  __shared__ f32x4 red[8][8][64];                // 64 KiB reduction scratch
  __shared__ f16 T[64 * 64];                     // 8 KiB output transpose tile

  const int bid = blockIdx.x;
  const int tid = threadIdx.x;
  const int wv = tid >> 6, lane = tid & 63;
  const int lr = lane & 15, lk = (lane >> 4) * 8;

  int* flags = (int*)(ws + FLAGS_OFF);
  f16* H0b = (f16*)(ws + H0_OFF);
  f16* H1b = H0b + (size_t)NBUF * HSLOT_H;
  const f16* Xp = (const f16*)(ws + XP_OFF);

  const bool isL0 = bid < 128;
  const int u = isL0 ? bid : bid - 128;
  const int cslice = (u & 7) * 4 + ((u >> 3) & 3);   // 4 col-slices per XCD
  const int m0 = (u >> 5) * 64;
  const int n0 = cslice * 64;
  const f16* Bst = (const f16*)(ws + (isL0 ? B0S_OFF : B1S_OFF));
  const int kcgb = isL0 ? wv * 9 : wv * 16;          // wave's first global K32 chunk
  const float* bias = isL0 ? b0v : b1v;

  const f16* bp = Bst + ((size_t)cslice * (isL0 ? NKC0 : NKC1) + kcgb) * 2048 + lane * 8;

  size_t aoff[4], xoff[4];
#pragma unroll
  for (int rf = 0; rf < 4; ++rf)
    aoff[rf] = (size_t)(m0 + rf * 16 + lr) * 2048 + lk;

  for (int p = 0; p <= 80; ++p) {
    const f16* Hr0 = H0b + (size_t)(p % NBUF) * HSLOT_H;              // h0[p-1]
    const f16* Hr1 = H1b + (size_t)((p >= 1 ? (p - 1) % NBUF : 0)) * HSLOT_H; // h1[p-2]
    f16* Hw = isL0 ? H0b + (size_t)((p + 1) % NBUF) * HSLOT_H         // h0[p]
                   : H1b + (size_t)(p % NBUF) * HSLOT_H;              // h1[p-1]
    const bool active = isL0 ? (p < 80) : true;
    const bool fzero  = (!isL0) && (p == 0);

    f32x4 acc[4][4];
#pragma unroll
    for (int a = 0; a < 4; ++a)
#pragma unroll
      for (int b = 0; b < 4; ++b) acc[a][b] = {0.f, 0.f, 0.f, 0.f};

    if (active && !fzero) {
      if (isL0) {
#pragma unroll
        for (int rf = 0; rf < 4; ++rf)
          xoff[rf] = ((size_t)p * 256 + m0 + rf * 16 + lr) * EPAD + lk;
        if (wv < 7) ktile<9, true, COH>(Hr0, Xp, bp, aoff, xoff, wv * 288, acc);
        else        ktile<5, true, COH>(Hr0, Xp, bp, aoff, xoff, wv * 288, acc);
      } else {
        // waves 0-3: K 0..2047 from h0[p-1]; waves 4-7: K 2048..4095 from h1[p-2]
        const f16* Ab = (wv < 4) ? Hr0 : Hr1;
        ktile<16, false, COH>(Ab, Xp, bp, aoff, xoff, (wv & 3) * 512, acc);
      }
    }

    if (active) {
      // 2-pass 8-way K-reduction, then bias+tanh -> swizzled f16 LDS tile
#pragma unroll
      for (int t = 0; t < 2; ++t) {
        if (t) __syncthreads();            // pass-0 readers done before rewrite
#pragma unroll
        for (int rr = 0; rr < 2; ++rr)
#pragma unroll
          for (int cf = 0; cf < 4; ++cf)
            red[wv][rr * 4 + cf][lane] = acc[2 * t + rr][cf];
        __syncthreads();
        {
          const int rf = 2 * t + (wv >> 2), cf = wv & 3;  // frag idx = wv
          f32x4 s = red[0][wv][lane];
#pragma unroll
          for (int ow = 1; ow < 8; ++ow) s += red[ow][wv][lane];
          const int tcol = cf * 16 + lr;
          const float bv = bias[n0 + tcol];
          const int trow = rf * 16 + (lane >> 4) * 4;
#pragma unroll
          for (int r = 0; r < 4; ++r) {
            const float v = fzero ? 0.f : tanh_fast(s[r] + bv);
            T[(trow + r) * 64 + (tcol ^ (((trow + r) & 3) << 4))] = (f16)v;
          }
        }
      }
      __syncthreads();
      // coalesced write-through store: one 16B sc0sc1 store per thread
      {
        const int row = tid >> 3, c8 = (tid & 7) * 8;
        f16x8 val = *(const f16x8*)(T + row * 64 + (c8 ^ ((row & 3) << 4)));
        stg16_coh(Hw + (size_t)(m0 + row) * 2048 + n0 + c8, val);
      }
    }
    if (p < 80) gbar(flags, p + 1);
  }
}

// ---------------------------------------------------------------------------
// epilogue: logits = sigmoid(h1[79] @ Wo + bo) -> 256 fp32
// ---------------------------------------------------------------------------
__global__ __launch_bounds__(256) void logits_k(
    const f16* __restrict__ h1, const float* __restrict__ Wo,
    const float* __restrict__ bo, float* __restrict__ out)
{
  int row = blockIdx.x * 4 + (threadIdx.x >> 6);
  int lane = threadIdx.x & 63;
  const f16* hr = h1 + (size_t)row * 2048;
  float s = 0.f;
#pragma unroll
  for (int it = 0; it < 4; ++it) {
    int k = it * 512 + lane * 8;
    f16x8 hv = *(const f16x8*)(hr + k);
    const float4* wp = (const float4*)(Wo + k);
    float4 w0 = wp[0], w1 = wp[1];
    s += (float)hv[0] * w0.x + (float)hv[1] * w0.y + (float)hv[2] * w0.z + (float)hv[3] * w0.w;
    s += (float)hv[4] * w1.x + (float)hv[5] * w1.y + (float)hv[6] * w1.z + (float)hv[7] * w1.w;
  }
#pragma unroll
  for (int off = 32; off > 0; off >>= 1) s += __shfl_down(s, off);
  if (lane == 0) out[row] = 1.f / (1.f + __expf(-(s + bo[0])));
}

// ---------------------------------------------------------------------------
extern "C" void kernel_launch(void* const* d_in, const int* in_sizes, int n_in,
                              void* d_out, int out_size, void* d_ws, size_t ws_size,
                              hipStream_t stream)
{
  (void)in_sizes; (void)n_in; (void)out_size;
  const int*   inputs = (const int*)d_in[0];
  const float* emb    = (const float*)d_in[1];
  const float* W0     = (const float*)d_in[2];
  const float* U0     = (const float*)d_in[3];
  const float* b0     = (const float*)d_in[4];
  const float* W1     = (const float*)d_in[5];
  const float* U1     = (const float*)d_in[6];
  const float* b1     = (const float*)d_in[7];
  const float* Wo     = (const float*)d_in[8];
  const float* bo     = (const float*)d_in[9];
  char* ws = (char*)d_ws;
  if (ws_size < WS_MIN) return;   // visible validation failure if too small

  const bool full = (ws_size >= WS_FULL);
  const int  nbuf = full ? 81 : 3;

  // zero flags + the two t=-1 init slots (slot 0 of H0 and H1)
  hipMemsetAsync(ws + FLAGS_OFF, 0, 1024, stream);
  hipMemsetAsync(ws + H0_OFF, 0, HSLOT, stream);
  hipMemsetAsync(ws + H0_OFF + (size_t)nbuf * HSLOT, 0, HSLOT, stream);

  fmt_weights<<<6272, 256, 0, stream>>>(W0, U0, W1, U1, ws);
  embed_k<<<5120, 256, 0, stream>>>(inputs, emb, ws);
  if (full) rnn_persist<81, false><<<NWG, 512, 0, stream>>>(b0, b1, ws);
  else      rnn_persist<3,  true ><<<NWG, 512, 0, stream>>>(b0, b1, ws);

  const f16* h1f = (const f16*)(ws + H0_OFF + (size_t)nbuf * HSLOT
                                + (size_t)(80 % nbuf) * HSLOT);
  logits_k<<<64, 256, 0, stream>>>(h1f, Wo, bo, (float*)d_out);
}